// Round 2
// baseline (6719.687 us; speedup 1.0000x reference)
//
#include <hip/hip_runtime.h>
#include <cstdint>
#include <cstddef>

#define B_   4
#define S_   1024
#define D_   512
#define H_   8
#define HD_  64
#define DFF_ 2048
#define L_   4
#define M_   (B_ * S_)   // 4096

// ---------------- RMSNorm: one block per row (D=512, 256 thr x float2) ----------------
__global__ __launch_bounds__(256) void rmsnorm_kernel(const float* __restrict__ x,
                                                      const float* __restrict__ w,
                                                      float* __restrict__ y) {
  const int row = blockIdx.x;
  const float2 v = ((const float2*)(x + (size_t)row * D_))[threadIdx.x];
  float ss = v.x * v.x + v.y * v.y;
  #pragma unroll
  for (int off = 32; off > 0; off >>= 1) ss += __shfl_down(ss, off);
  __shared__ float sred[4];
  if ((threadIdx.x & 63) == 0) sred[threadIdx.x >> 6] = ss;
  __syncthreads();
  const float tot = sred[0] + sred[1] + sred[2] + sred[3];
  const float scale = rsqrtf(tot * (1.0f / (float)D_) + 1.1920929e-07f);
  const float2 wv = ((const float2*)w)[threadIdx.x];
  float2 o;
  o.x = v.x * scale * wv.x;
  o.y = v.y * scale * wv.y;
  ((float2*)(y + (size_t)row * D_))[threadIdx.x] = o;
}

// ---------------- Tiled f32 GEMM: C[M,N] = A[M,K] @ W[K,N] (+C if accum) -------------
// 64x64 block tile, 256 threads, 4x4 per thread, K-tile 16.
__global__ __launch_bounds__(256) void gemm_f32_kernel(const float* __restrict__ A,
                                                       const float* __restrict__ W,
                                                       float* __restrict__ C,
                                                       const int N, const int K,
                                                       const int accum) {
  __shared__ float As[16][68];  // [kk][m] (A tile transposed)
  __shared__ float Bs[16][64];  // [kk][n]
  const int t = threadIdx.x;
  const int tx = t & 15, ty = t >> 4;
  const int bm = blockIdx.y * 64, bn = blockIdx.x * 64;
  const float* Ap = A + (size_t)(bm + (t >> 2)) * K + (t & 3) * 4;
  const float* Wp = W + (size_t)(t >> 4) * N + bn + (t & 15) * 4;
  float acc[4][4] = {};
  for (int kt = 0; kt < K; kt += 16) {
    const float4 av = *(const float4*)(Ap + kt);
    const float4 wv = *(const float4*)(Wp + (size_t)kt * N);
    __syncthreads();  // prev compute done before overwriting tiles
    const int kc = (t & 3) * 4;
    const int mi = t >> 2;
    As[kc + 0][mi] = av.x;
    As[kc + 1][mi] = av.y;
    As[kc + 2][mi] = av.z;
    As[kc + 3][mi] = av.w;
    *(float4*)&Bs[t >> 4][(t & 15) * 4] = wv;
    __syncthreads();
    #pragma unroll
    for (int kk = 0; kk < 16; ++kk) {
      const float4 a4 = *(const float4*)&As[kk][ty * 4];
      const float4 b4 = *(const float4*)&Bs[kk][tx * 4];
      const float a[4] = {a4.x, a4.y, a4.z, a4.w};
      const float b[4] = {b4.x, b4.y, b4.z, b4.w};
      #pragma unroll
      for (int i = 0; i < 4; ++i)
        #pragma unroll
        for (int j = 0; j < 4; ++j)
          acc[i][j] = fmaf(a[i], b[j], acc[i][j]);
    }
  }
  #pragma unroll
  for (int i = 0; i < 4; ++i) {
    float* cp = C + (size_t)(bm + ty * 4 + i) * N + bn + tx * 4;
    float4 o = {acc[i][0], acc[i][1], acc[i][2], acc[i][3]};
    if (accum) {
      const float4 old = *(const float4*)cp;
      o.x += old.x; o.y += old.y; o.z += old.z; o.w += old.w;
    }
    *(float4*)cp = o;
  }
}

// ---------------- Flash masked attention (f32) ----------------
// Grid: (S/64, H, B). Block 256. Q-tile 64 rows; iterate 16 K-tiles of 64.
// qkv: [q | k | v], each (B,S,D) with head-major inner dim (h*64+d).
// Mask dtype is runtime-detected via probe (full_mask is all-True):
//   bool (1B): probe byte[1] == 1   |   int32: probe byte[1] == 0
__global__ __launch_bounds__(256) void flash_attn_kernel(const float* __restrict__ qkv,
                                                         const unsigned char* __restrict__ mask,
                                                         const unsigned char* __restrict__ mask_probe,
                                                         float* __restrict__ att) {
  __shared__ float QsT[64][68];  // [d][q]
  __shared__ float KET[64][68];  // [d][k] for scores, then [k][q] for E
  __shared__ float Vs[64][68];   // [k][d]
  const int qt = blockIdx.x, h = blockIdx.y, b = blockIdx.z;
  const int t = threadIdx.x;
  const int tx = t & 15, ty = t >> 4;
  const int int32_mode = (mask_probe[1] == 0);  // uniform across grid
  const float* Q = qkv;
  const float* K = qkv + (size_t)M_ * D_;
  const float* V = qkv + (size_t)2 * M_ * D_;
  {
    const int q = t >> 2;
    const int d0 = (t & 3) * 16;
    const float* src = Q + ((size_t)(b * S_ + qt * 64 + q)) * D_ + h * HD_ + d0;
    #pragma unroll
    for (int c = 0; c < 4; ++c) {
      const float4 v4 = *(const float4*)(src + 4 * c);
      QsT[d0 + 4 * c + 0][q] = v4.x;
      QsT[d0 + 4 * c + 1][q] = v4.y;
      QsT[d0 + 4 * c + 2][q] = v4.z;
      QsT[d0 + 4 * c + 3][q] = v4.w;
    }
  }
  float acc[4][4] = {};
  float mrow[4] = {-1e30f, -1e30f, -1e30f, -1e30f};
  float lrow[4] = {};
  for (int kt = 0; kt < S_ / 64; ++kt) {
    __syncthreads();  // Q loaded / prev PV done
    {
      const int r = t >> 2;
      const int d0 = (t & 3) * 16;
      const float* ksrc = K + ((size_t)(b * S_ + kt * 64 + r)) * D_ + h * HD_ + d0;
      const float* vsrc = V + ((size_t)(b * S_ + kt * 64 + r)) * D_ + h * HD_ + d0;
      #pragma unroll
      for (int c = 0; c < 4; ++c) {
        const float4 k4 = *(const float4*)(ksrc + 4 * c);
        KET[d0 + 4 * c + 0][r] = k4.x;
        KET[d0 + 4 * c + 1][r] = k4.y;
        KET[d0 + 4 * c + 2][r] = k4.z;
        KET[d0 + 4 * c + 3][r] = k4.w;
        *(float4*)&Vs[r][d0 + 4 * c] = *(const float4*)(vsrc + 4 * c);
      }
    }
    __syncthreads();
    // scores 4x4: rows q = ty*4+i, cols k = tx*4+j
    float sc[4][4] = {};
    #pragma unroll 8
    for (int d = 0; d < 64; ++d) {
      const float4 a4 = *(const float4*)&QsT[d][ty * 4];
      const float4 b4 = *(const float4*)&KET[d][tx * 4];
      const float a[4] = {a4.x, a4.y, a4.z, a4.w};
      const float bb[4] = {b4.x, b4.y, b4.z, b4.w};
      #pragma unroll
      for (int i = 0; i < 4; ++i)
        #pragma unroll
        for (int j = 0; j < 4; ++j)
          sc[i][j] = fmaf(a[i], bb[j], sc[i][j]);
    }
    // mask load (dtype-robust)
    float mf[4][4];
    #pragma unroll
    for (int i = 0; i < 4; ++i) {
      const size_t midx = ((size_t)(b * S_ + qt * 64 + ty * 4 + i)) * S_ + kt * 64 + tx * 4;
      if (int32_mode) {
        const int4 mv = *(const int4*)((const int*)mask + midx);
        mf[i][0] = mv.x ? 1.0f : 0.0f;
        mf[i][1] = mv.y ? 1.0f : 0.0f;
        mf[i][2] = mv.z ? 1.0f : 0.0f;
        mf[i][3] = mv.w ? 1.0f : 0.0f;
      } else {
        const uchar4 mv = *(const uchar4*)(mask + midx);
        mf[i][0] = mv.x ? 1.0f : 0.0f;
        mf[i][1] = mv.y ? 1.0f : 0.0f;
        mf[i][2] = mv.z ? 1.0f : 0.0f;
        mf[i][3] = mv.w ? 1.0f : 0.0f;
      }
    }
    // online softmax
    float e[4][4];
    #pragma unroll
    for (int i = 0; i < 4; ++i) {
      float neg[4];
      #pragma unroll
      for (int j = 0; j < 4; ++j)
        neg[j] = (mf[i][j] != 0.0f) ? sc[i][j] * 0.125f : -1e30f;
      float tm = fmaxf(fmaxf(neg[0], neg[1]), fmaxf(neg[2], neg[3]));
      tm = fmaxf(tm, __shfl_xor(tm, 1));
      tm = fmaxf(tm, __shfl_xor(tm, 2));
      tm = fmaxf(tm, __shfl_xor(tm, 4));
      tm = fmaxf(tm, __shfl_xor(tm, 8));
      const float mn = fmaxf(mrow[i], tm);
      const float corr = expf(mrow[i] - mn);
      mrow[i] = mn;
      float esum = 0.0f;
      #pragma unroll
      for (int j = 0; j < 4; ++j) {
        const float ev = expf(neg[j] - mn) * mf[i][j];
        e[i][j] = ev;
        esum += ev;
      }
      lrow[i] = lrow[i] * corr + esum;
      #pragma unroll
      for (int j = 0; j < 4; ++j) acc[i][j] *= corr;
    }
    __syncthreads();  // scores done reading KET
    #pragma unroll
    for (int i = 0; i < 4; ++i)
      #pragma unroll
      for (int j = 0; j < 4; ++j)
        KET[tx * 4 + j][ty * 4 + i] = e[i][j];  // E transposed: [k][q]
    __syncthreads();
    // PV: out rows q = ty*4+i, cols d = tx*4+j
    #pragma unroll 8
    for (int kp = 0; kp < 64; ++kp) {
      const float4 e4 = *(const float4*)&KET[kp][ty * 4];
      const float4 v4 = *(const float4*)&Vs[kp][tx * 4];
      const float ee[4] = {e4.x, e4.y, e4.z, e4.w};
      const float vv[4] = {v4.x, v4.y, v4.z, v4.w};
      #pragma unroll
      for (int i = 0; i < 4; ++i)
        #pragma unroll
        for (int j = 0; j < 4; ++j)
          acc[i][j] = fmaf(ee[i], vv[j], acc[i][j]);
    }
  }
  #pragma unroll
  for (int i = 0; i < 4; ++i) {
    float l = lrow[i];
    l += __shfl_xor(l, 1);
    l += __shfl_xor(l, 2);
    l += __shfl_xor(l, 4);
    l += __shfl_xor(l, 8);
    const float inv = 1.0f / fmaxf(l, 1e-20f);
    float* op = att + ((size_t)(b * S_ + qt * 64 + ty * 4 + i)) * D_ + h * HD_ + tx * 4;
    const float4 o = {acc[i][0] * inv, acc[i][1] * inv, acc[i][2] * inv, acc[i][3] * inv};
    *(float4*)op = o;
  }
}

// ---------------- SiLU(g)*u elementwise ----------------
__global__ __launch_bounds__(256) void silu_mul_kernel(float* __restrict__ g,
                                                       const float* __restrict__ u,
                                                       const int n4) {
  const int i = blockIdx.x * 256 + threadIdx.x;
  if (i < n4) {
    float4 gv = ((const float4*)g)[i];
    const float4 uv = ((const float4*)u)[i];
    gv.x = gv.x / (1.0f + expf(-gv.x)) * uv.x;
    gv.y = gv.y / (1.0f + expf(-gv.y)) * uv.y;
    gv.z = gv.z / (1.0f + expf(-gv.z)) * uv.z;
    gv.w = gv.w / (1.0f + expf(-gv.w)) * uv.w;
    ((float4*)g)[i] = gv;
  }
}

extern "C" void kernel_launch(void* const* d_in, const int* in_sizes, int n_in,
                              void* d_out, int out_size, void* d_ws, size_t ws_size,
                              hipStream_t stream) {
  const float* x        = (const float*)d_in[0];
  const float* norm_w   = (const float*)d_in[1];
  const float* attn_w   = (const float*)d_in[2];
  const float* ffn_up   = (const float*)d_in[3];
  const float* ffn_gate = (const float*)d_in[4];
  const float* ffn_down = (const float*)d_in[5];
  const unsigned char* masks[4] = {
      (const unsigned char*)d_in[6], (const unsigned char*)d_in[7],
      (const unsigned char*)d_in[8], (const unsigned char*)d_in[9]};
  const unsigned char* mask_probe = (const unsigned char*)d_in[9];  // full_mask: all True

  float* h = (float*)d_out;      // hidden state lives in d_out
  float* ws = (float*)d_ws;
  // Workspace layout (72 MB total):
  //   attn phase: y (8MB) | qkv (24MB) | att (8MB)
  //   ffn  phase: y (8MB) | g (32MB, overlaps qkv+att) | u (32MB)
  float* y   = ws;                          // M*D
  float* qkv = y + (size_t)M_ * D_;         // 3*M*D
  float* att = qkv + (size_t)3 * M_ * D_;   // M*D
  float* g   = qkv;                         // M*DFF (reuses qkv+att region)
  float* u   = qkv + (size_t)M_ * DFF_;     // M*DFF

  hipMemcpyAsync(h, x, sizeof(float) * (size_t)M_ * D_, hipMemcpyDeviceToDevice, stream);

  const dim3 blk(256);
  for (int l = 0; l < L_; ++l) {
    for (int i = 0; i < 4; ++i) {
      rmsnorm_kernel<<<M_, blk, 0, stream>>>(h, norm_w + (size_t)(l * 5 + i) * D_, y);
      const float* wb = attn_w + (size_t)((l * 4 + i) * 4) * D_ * D_;
      gemm_f32_kernel<<<dim3(D_ / 64, M_ / 64), blk, 0, stream>>>(
          y, wb, qkv, D_, D_, 0);
      gemm_f32_kernel<<<dim3(D_ / 64, M_ / 64), blk, 0, stream>>>(
          y, wb + (size_t)D_ * D_, qkv + (size_t)M_ * D_, D_, D_, 0);
      gemm_f32_kernel<<<dim3(D_ / 64, M_ / 64), blk, 0, stream>>>(
          y, wb + (size_t)2 * D_ * D_, qkv + (size_t)2 * M_ * D_, D_, D_, 0);
      flash_attn_kernel<<<dim3(S_ / 64, H_, B_), blk, 0, stream>>>(qkv, masks[i], mask_probe, att);
      gemm_f32_kernel<<<dim3(D_ / 64, M_ / 64), blk, 0, stream>>>(
          att, wb + (size_t)3 * D_ * D_, h, D_, D_, 1);
    }
    rmsnorm_kernel<<<M_, blk, 0, stream>>>(h, norm_w + (size_t)(l * 5 + 4) * D_, y);
    gemm_f32_kernel<<<dim3(DFF_ / 64, M_ / 64), blk, 0, stream>>>(
        y, ffn_gate + (size_t)l * D_ * DFF_, g, DFF_, D_, 0);
    gemm_f32_kernel<<<dim3(DFF_ / 64, M_ / 64), blk, 0, stream>>>(
        y, ffn_up + (size_t)l * D_ * DFF_, u, DFF_, D_, 0);
    silu_mul_kernel<<<(M_ * DFF_ / 4 + 255) / 256, blk, 0, stream>>>(g, u, M_ * DFF_ / 4);
    gemm_f32_kernel<<<dim3(D_ / 64, M_ / 64), blk, 0, stream>>>(
        g, ffn_down + (size_t)l * DFF_ * D_, h, D_, DFF_, 1);
  }
}

// Round 4
// 2051.399 us; speedup vs baseline: 3.2757x; 3.2757x over previous
//
#include <hip/hip_runtime.h>
#include <cstdint>
#include <cstddef>

#define B_   4
#define S_   1024
#define D_   512
#define H_   8
#define HD_  64
#define DFF_ 2048
#define L_   4
#define M_   (B_ * S_)   // 4096

typedef unsigned long long ull;
typedef __attribute__((ext_vector_type(8))) short bf16x8;
typedef __attribute__((ext_vector_type(4))) float f32x4;

__device__ __forceinline__ ushort f2bf(float f) {
  uint32_t u = __float_as_uint(f);
  u += 0x7fffu + ((u >> 16) & 1u);   // RNE
  return (ushort)(u >> 16);
}
__device__ __forceinline__ float bf2f(ushort b) {
  return __uint_as_float(((uint32_t)b) << 16);
}
__device__ __forceinline__ void g2lds16(const void* g, void* l) {
  __builtin_amdgcn_global_load_lds((const __attribute__((address_space(1))) unsigned int*)g,
                                   (__attribute__((address_space(3))) unsigned int*)l, 16, 0, 0);
}

// ---------------- weight transpose+cast: in f32 [R][C] -> out bf16 [C][R] ----------------
__global__ __launch_bounds__(256) void wtrans_kernel(const float* __restrict__ in,
                                                     ushort* __restrict__ out,
                                                     int R, int C, size_t ims, size_t oms) {
  __shared__ float tile[32][33];
  const int tx = threadIdx.x & 31, ty = threadIdx.x >> 5;  // 32x8
  const int c0 = blockIdx.x * 32, r0 = blockIdx.y * 32;
  const float* ip = in + (size_t)blockIdx.z * ims;
  ushort* op = out + (size_t)blockIdx.z * oms;
  #pragma unroll
  for (int i = 0; i < 4; ++i) tile[ty + 8 * i][tx] = ip[(size_t)(r0 + ty + 8 * i) * C + c0 + tx];
  __syncthreads();
  #pragma unroll
  for (int i = 0; i < 4; ++i) op[(size_t)(c0 + ty + 8 * i) * R + r0 + tx] = f2bf(tile[tx][ty + 8 * i]);
}

// ---------------- mask pack: (int32|bool)[4096][1024] -> uint64 [4096][16] per mask -------
__global__ __launch_bounds__(256) void maskpack_kernel(const void* m0, const void* m1,
                                                       const void* m2, const void* m3,
                                                       ull* __restrict__ out,
                                                       const unsigned char* __restrict__ probe) {
  const int mi = blockIdx.y;
  const void* mp = (mi == 0) ? m0 : (mi == 1) ? m1 : (mi == 2) ? m2 : m3;
  const int wid = blockIdx.x * 256 + threadIdx.x;  // 0..65535
  const int row = wid >> 4, ch = wid & 15;
  ull bits = 0;
  if (probe[1] == 0) {  // int32 masks
    const int4* p = (const int4*)mp + (((size_t)row * 1024 + ch * 64) >> 2);
    #pragma unroll
    for (int k = 0; k < 16; ++k) {
      const int4 v = p[k];
      bits |= (ull)(v.x != 0) << (k * 4 + 0);
      bits |= (ull)(v.y != 0) << (k * 4 + 1);
      bits |= (ull)(v.z != 0) << (k * 4 + 2);
      bits |= (ull)(v.w != 0) << (k * 4 + 3);
    }
  } else {  // bool (1B) masks
    const uint4* p = (const uint4*)((const unsigned char*)mp + (size_t)row * 1024 + ch * 64);
    #pragma unroll
    for (int k = 0; k < 4; ++k) {
      const uint4 v = p[k];
      const uint32_t w4[4] = {v.x, v.y, v.z, v.w};
      #pragma unroll
      for (int w = 0; w < 4; ++w)
        #pragma unroll
        for (int bb = 0; bb < 4; ++bb)
          bits |= (ull)(((w4[w] >> (8 * bb)) & 0xffu) ? 1 : 0) << (k * 16 + w * 4 + bb);
    }
  }
  out[(size_t)mi * 65536 + wid] = bits;
}

// ---------------- RMSNorm: f32 in -> bf16 out ----------------
__global__ __launch_bounds__(256) void rmsnorm_kernel(const float* __restrict__ x,
                                                      const float* __restrict__ w,
                                                      ushort* __restrict__ y) {
  const int row = blockIdx.x;
  const float2 v = ((const float2*)(x + (size_t)row * D_))[threadIdx.x];
  float ss = v.x * v.x + v.y * v.y;
  #pragma unroll
  for (int off = 32; off > 0; off >>= 1) ss += __shfl_down(ss, off);
  __shared__ float sred[4];
  if ((threadIdx.x & 63) == 0) sred[threadIdx.x >> 6] = ss;
  __syncthreads();
  const float tot = sred[0] + sred[1] + sred[2] + sred[3];
  const float scale = rsqrtf(tot * (1.0f / (float)D_) + 1.1920929e-07f);
  const float2 wv = ((const float2*)w)[threadIdx.x];
  const uint32_t o = (uint32_t)f2bf(v.x * scale * wv.x) | ((uint32_t)f2bf(v.y * scale * wv.y) << 16);
  ((uint32_t*)(y + (size_t)row * D_))[threadIdx.x] = o;
}

// ---------------- bf16 MFMA GEMM: C[M,N] = A[M,K] @ Wt[N,K]^T ----------------
// 128x128 tile, BK=64, 256 thr = 4 waves (2x2 of 64x64).
// m97-canon single-buffer 2-barrier K-loop (race-hardened).
// mode 0: write bf16 C (ldc); mode 1: f32 C += (residual accumulate).
__global__ __launch_bounds__(256) void gemm_bf16_kernel(const ushort* __restrict__ A, int lda,
                                                        const ushort* __restrict__ Wt, int K,
                                                        void* __restrict__ Cout, int ldc,
                                                        int mode) {
  __shared__ __align__(16) uint8_t lds[32768];  // [A 16KB | B 16KB]
  const int t = threadIdx.x, l = t & 63, wv = t >> 6;
  const int m0 = blockIdx.y * 128, n0 = blockIdx.x * 128;
  const int wrow = (wv >> 1) * 64, wcol = (wv & 1) * 64;

  f32x4 acc[4][4] = {};
  const int nk = K / 64;
  for (int kt = 0; kt < nk; ++kt) {
    __syncthreads();  // prev compute done reading lds
    {
      const int k0 = kt * 64;
      #pragma unroll
      for (int i = 0; i < 4; ++i) {
        const int row = wv * 32 + i * 8 + (l >> 3);
        const int g = (l & 7) ^ (row & 7);
        g2lds16(A + (size_t)(m0 + row) * lda + k0 + g * 8, &lds[(wv * 32 + i * 8) * 128]);
        g2lds16(Wt + (size_t)(n0 + row) * K + k0 + g * 8, &lds[16384 + (wv * 32 + i * 8) * 128]);
      }
    }
    __syncthreads();  // staging complete (vmcnt drained at barrier)
    const uint8_t* Ab = &lds[0];
    const uint8_t* Bb = &lds[16384];
    #pragma unroll
    for (int ks = 0; ks < 2; ++ks) {
      bf16x8 af[4], bfr[4];
      #pragma unroll
      for (int fm = 0; fm < 4; ++fm) {
        const int row = wrow + fm * 16 + (l & 15);
        const int chunk = ((l >> 4) + ks * 4) ^ (row & 7);
        af[fm] = *(const bf16x8*)&Ab[row * 128 + chunk * 16];
      }
      #pragma unroll
      for (int fn = 0; fn < 4; ++fn) {
        const int row = wcol + fn * 16 + (l & 15);
        const int chunk = ((l >> 4) + ks * 4) ^ (row & 7);
        bfr[fn] = *(const bf16x8*)&Bb[row * 128 + chunk * 16];
      }
      #pragma unroll
      for (int fm = 0; fm < 4; ++fm)
        #pragma unroll
        for (int fn = 0; fn < 4; ++fn)
          acc[fm][fn] = __builtin_amdgcn_mfma_f32_16x16x32_bf16(af[fm], bfr[fn], acc[fm][fn], 0, 0, 0);
    }
  }
  // epilogue: C row=(l>>4)*4+r, col=l&15
  #pragma unroll
  for (int fm = 0; fm < 4; ++fm)
    #pragma unroll
    for (int fn = 0; fn < 4; ++fn)
      #pragma unroll
      for (int r = 0; r < 4; ++r) {
        const int row = m0 + wrow + fm * 16 + (l >> 4) * 4 + r;
        const int col = n0 + wcol + fn * 16 + (l & 15);
        const float v = acc[fm][fn][r];
        if (mode == 0) {
          ((ushort*)Cout)[(size_t)row * ldc + col] = f2bf(v);
        } else {
          float* p = (float*)Cout + (size_t)row * ldc + col;
          *p += v;
        }
      }
}

// ---------------- V transpose: qkv cols [1024..1536) -> vt[b,h,d,s] (bf16) ----------------
__global__ __launch_bounds__(256) void vtrans_kernel(const ushort* __restrict__ qkv,
                                                     ushort* __restrict__ vt) {
  __shared__ __align__(16) ushort tile[64][80];
  const int st = blockIdx.x, bh = blockIdx.y;
  const int b = bh >> 3, h = bh & 7;
  const int t = threadIdx.x;
  #pragma unroll
  for (int i = 0; i < 2; ++i) {
    const int id = t + 256 * i;  // 0..511
    const int s = id >> 3, c8 = id & 7;
    const ushort* src = qkv + (size_t)(b * S_ + st * 64 + s) * 1536 + 1024 + h * 64 + c8 * 8;
    *(bf16x8*)&tile[s][c8 * 8] = *(const bf16x8*)src;
  }
  __syncthreads();
  #pragma unroll
  for (int i = 0; i < 2; ++i) {
    const int id = t + 256 * i;
    const int d = id >> 3, s8 = id & 7;
    bf16x8 v8;
    #pragma unroll
    for (int j = 0; j < 8; ++j) v8[j] = (short)tile[s8 * 8 + j][d];
    *(bf16x8*)(vt + (size_t)(bh * 64 + d) * S_ + st * 64 + s8 * 8) = v8;
  }
}

// ---------------- Flash masked attention, bf16 MFMA ----------------
// Grid (S/64, H, B), 256 thr = 4 waves; wave w owns q rows w*16..w*16+15.
__global__ __launch_bounds__(256) void flash_mfma_kernel(const ushort* __restrict__ qkv,
                                                         const ushort* __restrict__ vt,
                                                         const ull* __restrict__ pm,
                                                         ushort* __restrict__ att) {
  __shared__ __align__(16) uint8_t Kt[64 * 128];
  __shared__ __align__(16) uint8_t Vl[64 * 128];
  __shared__ __align__(16) uint8_t Pl[64 * 128];
  __shared__ ull Ml[64];
  const int qt = blockIdx.x, h = blockIdx.y, b = blockIdx.z;
  const int t = threadIdx.x, l = t & 63, wv = t >> 6;

  bf16x8 qf[2];
  {
    const ushort* qrow =
        qkv + (size_t)(b * S_ + qt * 64 + wv * 16 + (l & 15)) * 1536 + h * HD_ + (l >> 4) * 8;
    qf[0] = *(const bf16x8*)qrow;
    qf[1] = *(const bf16x8*)(qrow + 32);
  }
  f32x4 oacc[4] = {};
  float mrow[4] = {-1e30f, -1e30f, -1e30f, -1e30f};
  float lrow[4] = {};

  for (int kt2 = 0; kt2 < S_ / 64; ++kt2) {
    __syncthreads();  // prev tile's PV reads drained
    #pragma unroll
    for (int i = 0; i < 2; ++i) {
      const int row = i * 32 + wv * 8 + (l >> 3);
      const int g = (l & 7) ^ (row & 7);
      g2lds16(qkv + (size_t)(b * S_ + kt2 * 64 + row) * 1536 + 512 + h * HD_ + g * 8,
              &Kt[(i * 32 + wv * 8) * 128]);
      g2lds16(vt + (size_t)((b * H_ + h) * HD_ + row) * S_ + kt2 * 64 + g * 8,
              &Vl[(i * 32 + wv * 8) * 128]);
    }
    if (t < 64) Ml[t] = pm[(size_t)(b * S_ + qt * 64 + t) * 16 + kt2];
    __syncthreads();  // staging complete

    // ---- S = Q K^T ----
    f32x4 sacc[4] = {};
    bf16x8 kf[4][2];
    #pragma unroll
    for (int fn = 0; fn < 4; ++fn)
      #pragma unroll
      for (int ks = 0; ks < 2; ++ks) {
        const int row = fn * 16 + (l & 15);
        const int chunk = ((l >> 4) + ks * 4) ^ (row & 7);
        kf[fn][ks] = *(const bf16x8*)&Kt[row * 128 + chunk * 16];
      }
    __builtin_amdgcn_s_setprio(1);
    #pragma unroll
    for (int fn = 0; fn < 4; ++fn)
      #pragma unroll
      for (int ks = 0; ks < 2; ++ks)
        sacc[fn] = __builtin_amdgcn_mfma_f32_16x16x32_bf16(qf[ks], kf[fn][ks], sacc[fn], 0, 0, 0);
    __builtin_amdgcn_s_setprio(0);

    // ---- online softmax (rows q=(l>>4)*4+r, cols kv=(l&15)+fn*16) ----
    float p[4][4];
    float corr[4];
    #pragma unroll
    for (int r = 0; r < 4; ++r) {
      const ull mw = Ml[wv * 16 + (l >> 4) * 4 + r];
      float s[4];
      int bit[4];
      float mx = -1e30f;
      #pragma unroll
      for (int fn = 0; fn < 4; ++fn) {
        bit[fn] = (int)((mw >> ((l & 15) + fn * 16)) & 1ull);
        const float sv = bit[fn] ? sacc[fn][r] * 0.125f : -1e30f;
        s[fn] = sv;
        mx = fmaxf(mx, sv);
      }
      mx = fmaxf(mx, __shfl_xor(mx, 1));
      mx = fmaxf(mx, __shfl_xor(mx, 2));
      mx = fmaxf(mx, __shfl_xor(mx, 4));
      mx = fmaxf(mx, __shfl_xor(mx, 8));
      const float mn = fmaxf(mrow[r], mx);
      corr[r] = __expf(mrow[r] - mn);
      mrow[r] = mn;
      float rs = 0.0f;
      #pragma unroll
      for (int fn = 0; fn < 4; ++fn) {
        const float e = bit[fn] ? __expf(s[fn] - mn) : 0.0f;
        p[fn][r] = e;
        rs += e;
      }
      rs += __shfl_xor(rs, 1);
      rs += __shfl_xor(rs, 2);
      rs += __shfl_xor(rs, 4);
      rs += __shfl_xor(rs, 8);
      lrow[r] = lrow[r] * corr[r] + rs;
    }
    #pragma unroll
    for (int fd = 0; fd < 4; ++fd)
      #pragma unroll
      for (int r = 0; r < 4; ++r) oacc[fd][r] *= corr[r];

    // ---- P -> LDS (bf16, swizzled; own wave's 16 rows) ----
    #pragma unroll
    for (int fn = 0; fn < 4; ++fn)
      #pragma unroll
      for (int r = 0; r < 4; ++r) {
        const int ql = (l >> 4) * 4 + r;
        const int kv = (l & 15) + fn * 16;
        *(ushort*)&Pl[(wv * 16 + ql) * 128 + (((kv >> 3) ^ (ql & 7)) * 16) + (kv & 7) * 2] =
            f2bf(p[fn][r]);
      }
    __syncthreads();  // race-hardening: Pl writes visible before PV fragment reads

    // ---- O += P V ----
    bf16x8 pa[2];
    #pragma unroll
    for (int ks = 0; ks < 2; ++ks) {
      const int row = wv * 16 + (l & 15);
      const int chunk = ((l >> 4) + ks * 4) ^ ((l & 15) & 7);
      pa[ks] = *(const bf16x8*)&Pl[row * 128 + chunk * 16];
    }
    bf16x8 vf[4][2];
    #pragma unroll
    for (int fd = 0; fd < 4; ++fd)
      #pragma unroll
      for (int ks = 0; ks < 2; ++ks) {
        const int row = fd * 16 + (l & 15);
        const int chunk = ((l >> 4) + ks * 4) ^ (row & 7);
        vf[fd][ks] = *(const bf16x8*)&Vl[row * 128 + chunk * 16];
      }
    __builtin_amdgcn_s_setprio(1);
    #pragma unroll
    for (int fd = 0; fd < 4; ++fd)
      #pragma unroll
      for (int ks = 0; ks < 2; ++ks)
        oacc[fd] = __builtin_amdgcn_mfma_f32_16x16x32_bf16(pa[ks], vf[fd][ks], oacc[fd], 0, 0, 0);
    __builtin_amdgcn_s_setprio(0);
  }

  #pragma unroll
  for (int r = 0; r < 4; ++r) {
    const float inv = 1.0f / fmaxf(lrow[r], 1e-20f);
    #pragma unroll
    for (int fd = 0; fd < 4; ++fd) {
      att[(size_t)(b * S_ + qt * 64 + wv * 16 + (l >> 4) * 4 + r) * D_ + h * HD_ + (l & 15) +
          fd * 16] = f2bf(oacc[fd][r] * inv);
    }
  }
}

// ---------------- SiLU(gate)*up, in-place into gate half of gu [M][4096] bf16 -----------
__global__ __launch_bounds__(256) void silu_kernel(ushort* __restrict__ gu) {
  const int idx = blockIdx.x * 256 + threadIdx.x;  // 0 .. M*2048/8-1
  const int row = idx >> 8, c8 = idx & 255;
  ushort* gp = gu + (size_t)row * 4096 + c8 * 8;
  const ushort* up = gp + 2048;
  bf16x8 g8 = *(const bf16x8*)gp;
  const bf16x8 u8 = *(const bf16x8*)up;
  #pragma unroll
  for (int j = 0; j < 8; ++j) {
    const float g = bf2f((ushort)g8[j]);
    const float u = bf2f((ushort)u8[j]);
    g8[j] = (short)f2bf(g / (1.0f + __expf(-g)) * u);
  }
  *(bf16x8*)gp = g8;
}

extern "C" void kernel_launch(void* const* d_in, const int* in_sizes, int n_in,
                              void* d_out, int out_size, void* d_ws, size_t ws_size,
                              hipStream_t stream) {
  const float* x        = (const float*)d_in[0];
  const float* norm_w   = (const float*)d_in[1];
  const float* attn_w   = (const float*)d_in[2];
  const float* ffn_up   = (const float*)d_in[3];
  const float* ffn_gate = (const float*)d_in[4];
  const float* ffn_down = (const float*)d_in[5];

  float* h = (float*)d_out;
  // ---- workspace layout (≈54.5 MB) ----
  ushort* wt_attn = (ushort*)d_ws;                    // [16][512][512] bf16 (per layer)
  ushort* wt_gu   = wt_attn + (size_t)16 * 512 * 512; // [4096][512] bf16 (per layer)
  ushort* wt_down = wt_gu + (size_t)4096 * 512;       // [512][2048] bf16 (per layer)
  ull*    pmask   = (ull*)(wt_down + (size_t)512 * 2048);  // [4][4096][16]
  ushort* y       = (ushort*)(pmask + 4 * 65536);     // [M][512]
  ushort* qkvbuf  = y + (size_t)M_ * 512;             // [M][1536]
  ushort* vt      = qkvbuf + (size_t)M_ * 1536;       // [32][64][1024]
  ushort* att     = vt + (size_t)M_ * 512;            // [M][512]
  ushort* gu      = qkvbuf;                           // [M][4096] (overlaps qkv/vt/att)

  hipMemcpyAsync(h, x, sizeof(float) * (size_t)M_ * D_, hipMemcpyDeviceToDevice, stream);

  const dim3 blk(256);
  maskpack_kernel<<<dim3(256, 4), blk, 0, stream>>>(d_in[6], d_in[7], d_in[8], d_in[9], pmask,
                                                    (const unsigned char*)d_in[9]);

  for (int l = 0; l < L_; ++l) {
    // per-layer weight prep (transpose + bf16 cast)
    wtrans_kernel<<<dim3(16, 16, 16), blk, 0, stream>>>(
        attn_w + (size_t)l * 16 * 512 * 512, wt_attn, 512, 512, 512 * 512, 512 * 512);
    wtrans_kernel<<<dim3(64, 16, 1), blk, 0, stream>>>(
        ffn_gate + (size_t)l * 512 * 2048, wt_gu, 512, 2048, 0, 0);
    wtrans_kernel<<<dim3(64, 16, 1), blk, 0, stream>>>(
        ffn_up + (size_t)l * 512 * 2048, wt_gu + (size_t)2048 * 512, 512, 2048, 0, 0);
    wtrans_kernel<<<dim3(16, 64, 1), blk, 0, stream>>>(
        ffn_down + (size_t)l * 2048 * 512, wt_down, 2048, 512, 0, 0);

    for (int i = 0; i < 4; ++i) {
      rmsnorm_kernel<<<M_, blk, 0, stream>>>(h, norm_w + (size_t)(l * 5 + i) * D_, y);
      // fused QKV: N=1536
      gemm_bf16_kernel<<<dim3(12, 32), blk, 0, stream>>>(
          y, 512, wt_attn + (size_t)i * 4 * 512 * 512, 512, qkvbuf, 1536, 0);
      vtrans_kernel<<<dim3(16, 32), blk, 0, stream>>>(qkvbuf, vt);
      flash_mfma_kernel<<<dim3(16, 8, 4), blk, 0, stream>>>(qkvbuf, vt, pmask + (size_t)i * 65536,
                                                            att);
      // O-proj + residual
      gemm_bf16_kernel<<<dim3(4, 32), blk, 0, stream>>>(
          att, 512, wt_attn + (size_t)i * 4 * 512 * 512 + (size_t)1536 * 512, 512, h, 512, 1);
    }
    rmsnorm_kernel<<<M_, blk, 0, stream>>>(h, norm_w + (size_t)(l * 5 + 4) * D_, y);
    // fused gate|up: N=4096
    gemm_bf16_kernel<<<dim3(32, 32), blk, 0, stream>>>(y, 512, wt_gu, 512, gu, 4096, 0);
    silu_kernel<<<dim3(M_ * 2048 / 8 / 256), blk, 0, stream>>>(gu);
    // down + residual (A = gate half of gu, lda=4096)
    gemm_bf16_kernel<<<dim3(4, 32), blk, 0, stream>>>(gu, 4096, wt_down, 2048, h, 512, 1);
  }
}

// Round 6
// 1766.940 us; speedup vs baseline: 3.8030x; 1.1610x over previous
//
#include <hip/hip_runtime.h>
#include <cstdint>
#include <cstddef>

#define B_   4
#define S_   1024
#define D_   512
#define H_   8
#define HD_  64
#define DFF_ 2048
#define L_   4
#define M_   (B_ * S_)   // 4096

typedef unsigned long long ull;
typedef __attribute__((ext_vector_type(8))) short bf16x8;
typedef __attribute__((ext_vector_type(4))) float f32x4;

__device__ __forceinline__ ushort f2bf(float f) {
  uint32_t u = __float_as_uint(f);
  u += 0x7fffu + ((u >> 16) & 1u);   // RNE
  return (ushort)(u >> 16);
}
__device__ __forceinline__ float bf2f(ushort b) {
  return __uint_as_float(((uint32_t)b) << 16);
}
__device__ __forceinline__ void g2lds16(const void* g, void* l) {
  __builtin_amdgcn_global_load_lds((const __attribute__((address_space(1))) unsigned int*)g,
                                   (__attribute__((address_space(3))) unsigned int*)l, 16, 0, 0);
}

// ---------------- weight transpose+cast: in f32 [R][C] -> out bf16 [C][R] ----------------
__global__ __launch_bounds__(256) void wtrans_kernel(const float* __restrict__ in,
                                                     ushort* __restrict__ out,
                                                     int R, int C, size_t ims, size_t oms) {
  __shared__ float tile[32][33];
  const int tx = threadIdx.x & 31, ty = threadIdx.x >> 5;  // 32x8
  const int c0 = blockIdx.x * 32, r0 = blockIdx.y * 32;
  const float* ip = in + (size_t)blockIdx.z * ims;
  ushort* op = out + (size_t)blockIdx.z * oms;
  #pragma unroll
  for (int i = 0; i < 4; ++i) tile[ty + 8 * i][tx] = ip[(size_t)(r0 + ty + 8 * i) * C + c0 + tx];
  __syncthreads();
  #pragma unroll
  for (int i = 0; i < 4; ++i) op[(size_t)(c0 + ty + 8 * i) * R + r0 + tx] = f2bf(tile[tx][ty + 8 * i]);
}

// ---------------- mask pack: (int32|bool)[4096][1024] -> uint64 [4096][16] per mask -------
__global__ __launch_bounds__(256) void maskpack_kernel(const void* m0, const void* m1,
                                                       const void* m2, const void* m3,
                                                       ull* __restrict__ out,
                                                       const unsigned char* __restrict__ probe) {
  const int mi = blockIdx.y;
  const void* mp = (mi == 0) ? m0 : (mi == 1) ? m1 : (mi == 2) ? m2 : m3;
  const int wid = blockIdx.x * 256 + threadIdx.x;  // 0..65535
  const int row = wid >> 4, ch = wid & 15;
  ull bits = 0;
  if (probe[1] == 0) {  // int32 masks
    const int4* p = (const int4*)mp + (((size_t)row * 1024 + ch * 64) >> 2);
    #pragma unroll
    for (int k = 0; k < 16; ++k) {
      const int4 v = p[k];
      bits |= (ull)(v.x != 0) << (k * 4 + 0);
      bits |= (ull)(v.y != 0) << (k * 4 + 1);
      bits |= (ull)(v.z != 0) << (k * 4 + 2);
      bits |= (ull)(v.w != 0) << (k * 4 + 3);
    }
  } else {  // bool (1B) masks
    const uint4* p = (const uint4*)((const unsigned char*)mp + (size_t)row * 1024 + ch * 64);
    #pragma unroll
    for (int k = 0; k < 4; ++k) {
      const uint4 v = p[k];
      const uint32_t w4[4] = {v.x, v.y, v.z, v.w};
      #pragma unroll
      for (int w = 0; w < 4; ++w)
        #pragma unroll
        for (int bb = 0; bb < 4; ++bb)
          bits |= (ull)(((w4[w] >> (8 * bb)) & 0xffu) ? 1 : 0) << (k * 16 + w * 4 + bb);
    }
  }
  out[(size_t)mi * 65536 + wid] = bits;
}

// ---------------- RMSNorm: 1 wave per row, f32 in -> bf16 out; grid M/4 x 256 ------------
__global__ __launch_bounds__(256) void rmsnorm_kernel(const float* __restrict__ x,
                                                      const float* __restrict__ w,
                                                      ushort* __restrict__ y) {
  const int row = blockIdx.x * 4 + (threadIdx.x >> 6);
  const int l = threadIdx.x & 63;
  const float4* xr = (const float4*)(x + (size_t)row * D_);
  const float4 v0 = xr[l * 2], v1 = xr[l * 2 + 1];
  float ss = v0.x * v0.x + v0.y * v0.y + v0.z * v0.z + v0.w * v0.w +
             v1.x * v1.x + v1.y * v1.y + v1.z * v1.z + v1.w * v1.w;
  #pragma unroll
  for (int off = 32; off > 0; off >>= 1) ss += __shfl_xor(ss, off);
  const float scale = rsqrtf(ss * (1.0f / (float)D_) + 1.1920929e-07f);
  const float4* wr = (const float4*)w;
  const float4 w0 = wr[l * 2], w1 = wr[l * 2 + 1];
  bf16x8 o;
  o[0] = (short)f2bf(v0.x * scale * w0.x);
  o[1] = (short)f2bf(v0.y * scale * w0.y);
  o[2] = (short)f2bf(v0.z * scale * w0.z);
  o[3] = (short)f2bf(v0.w * scale * w0.w);
  o[4] = (short)f2bf(v1.x * scale * w1.x);
  o[5] = (short)f2bf(v1.y * scale * w1.y);
  o[6] = (short)f2bf(v1.z * scale * w1.z);
  o[7] = (short)f2bf(v1.w * scale * w1.w);
  *(bf16x8*)(y + (size_t)row * D_ + l * 8) = o;
}

// ---------------- bf16 MFMA GEMM: C[M,N] = A[M,K] @ Wt[N,K]^T ----------------
// BM x 128 tile, BK=64, 256 thr = 4 waves. m97-canon single-buffer 2-barrier K-loop.
// mode 1: f32 C += (residual). mode 2: QKV -> bf16 Q|K at ldc=1024 + V transposed into vt.
template <int BM>
__global__ __launch_bounds__(256) void gemm_bf16_kernel(const ushort* __restrict__ A, int lda,
                                                        const ushort* __restrict__ Wt, int K,
                                                        void* __restrict__ Cout, int ldc,
                                                        int mode, ushort* __restrict__ vt) {
  constexpr int MR = BM / 32;
  __shared__ __align__(16) uint8_t lds[BM * 128 + 16384];
  const int t = threadIdx.x, l = t & 63, wv = t >> 6;
  const int m0 = blockIdx.y * BM, n0 = blockIdx.x * 128;
  const int wrow = (wv >> 1) * (BM / 2), wcol = (wv & 1) * 64;

  f32x4 acc[MR][4] = {};
  const int nk = K / 64;
  for (int kt = 0; kt < nk; ++kt) {
    __syncthreads();  // prev compute done reading lds
    {
      const int k0 = kt * 64;
      #pragma unroll
      for (int i = 0; i < BM / 32; ++i) {
        const int row = wv * (BM / 4) + i * 8 + (l >> 3);
        const int g = (l & 7) ^ (row & 7);
        g2lds16(A + (size_t)(m0 + row) * lda + k0 + g * 8, &lds[(wv * (BM / 4) + i * 8) * 128]);
      }
      #pragma unroll
      for (int i = 0; i < 4; ++i) {
        const int row = wv * 32 + i * 8 + (l >> 3);
        const int g = (l & 7) ^ (row & 7);
        g2lds16(Wt + (size_t)(n0 + row) * K + k0 + g * 8,
                &lds[BM * 128 + (wv * 32 + i * 8) * 128]);
      }
    }
    __syncthreads();  // staging complete (vmcnt drained at barrier)
    const uint8_t* Ab = &lds[0];
    const uint8_t* Bb = &lds[BM * 128];
    #pragma unroll
    for (int ks = 0; ks < 2; ++ks) {
      bf16x8 af[MR], bfr[4];
      #pragma unroll
      for (int fm = 0; fm < MR; ++fm) {
        const int row = wrow + fm * 16 + (l & 15);
        const int chunk = ((l >> 4) + ks * 4) ^ (row & 7);
        af[fm] = *(const bf16x8*)&Ab[row * 128 + chunk * 16];
      }
      #pragma unroll
      for (int fn = 0; fn < 4; ++fn) {
        const int row = wcol + fn * 16 + (l & 15);
        const int chunk = ((l >> 4) + ks * 4) ^ (row & 7);
        bfr[fn] = *(const bf16x8*)&Bb[row * 128 + chunk * 16];
      }
      #pragma unroll
      for (int fm = 0; fm < MR; ++fm)
        #pragma unroll
        for (int fn = 0; fn < 4; ++fn)
          acc[fm][fn] = __builtin_amdgcn_mfma_f32_16x16x32_bf16(af[fm], bfr[fn], acc[fm][fn], 0, 0, 0);
    }
  }
  // epilogue: C row=(l>>4)*4+r, col=l&15
  #pragma unroll
  for (int fm = 0; fm < MR; ++fm)
    #pragma unroll
    for (int fn = 0; fn < 4; ++fn)
      #pragma unroll
      for (int r = 0; r < 4; ++r) {
        const int row = m0 + wrow + fm * 16 + (l >> 4) * 4 + r;
        const int col = n0 + wcol + fn * 16 + (l & 15);
        const float v = acc[fm][fn][r];
        if (mode == 1) {
          float* p = (float*)Cout + (size_t)row * ldc + col;
          *p += v;
        } else {  // mode 2: QKV
          if (col < 1024) {
            ((ushort*)Cout)[(size_t)row * ldc + col] = f2bf(v);
          } else {
            const int hh = (col - 1024) >> 6, dd = (col - 1024) & 63;
            const int bb = row >> 10, ss = row & 1023;
            vt[((size_t)(bb * 8 + hh) * 64 + dd) * 1024 + ss] = f2bf(v);
          }
        }
      }
}

// ---------------- fused gate|up GEMM + SiLU: sg[M][2048] = silu(y@Wg^T)*(y@Wu^T) ---------
// 128x128 tile per weight, stages A once; grid (16, 32).
__global__ __launch_bounds__(256) void gemm_gateup_kernel(const ushort* __restrict__ A,
                                                          const ushort* __restrict__ Wg,
                                                          const ushort* __restrict__ Wu,
                                                          ushort* __restrict__ sg) {
  __shared__ __align__(16) uint8_t lds[49152];  // A 16K | Bg 16K | Bu 16K
  const int t = threadIdx.x, l = t & 63, wv = t >> 6;
  const int m0 = blockIdx.y * 128, n0 = blockIdx.x * 128;
  const int wrow = (wv >> 1) * 64, wcol = (wv & 1) * 64;

  f32x4 accg[4][4] = {}, accu[4][4] = {};
  for (int kt = 0; kt < 8; ++kt) {
    __syncthreads();
    {
      const int k0 = kt * 64;
      #pragma unroll
      for (int i = 0; i < 4; ++i) {
        const int row = wv * 32 + i * 8 + (l >> 3);
        const int g = (l & 7) ^ (row & 7);
        g2lds16(A + (size_t)(m0 + row) * 512 + k0 + g * 8, &lds[(wv * 32 + i * 8) * 128]);
        g2lds16(Wg + (size_t)(n0 + row) * 512 + k0 + g * 8, &lds[16384 + (wv * 32 + i * 8) * 128]);
        g2lds16(Wu + (size_t)(n0 + row) * 512 + k0 + g * 8, &lds[32768 + (wv * 32 + i * 8) * 128]);
      }
    }
    __syncthreads();
    #pragma unroll
    for (int ks = 0; ks < 2; ++ks) {
      bf16x8 af[4], bf[4];
      #pragma unroll
      for (int fm = 0; fm < 4; ++fm) {
        const int row = wrow + fm * 16 + (l & 15);
        const int chunk = ((l >> 4) + ks * 4) ^ (row & 7);
        af[fm] = *(const bf16x8*)&lds[row * 128 + chunk * 16];
      }
      #pragma unroll
      for (int fn = 0; fn < 4; ++fn) {
        const int row = wcol + fn * 16 + (l & 15);
        const int chunk = ((l >> 4) + ks * 4) ^ (row & 7);
        bf[fn] = *(const bf16x8*)&lds[16384 + row * 128 + chunk * 16];
      }
      #pragma unroll
      for (int fm = 0; fm < 4; ++fm)
        #pragma unroll
        for (int fn = 0; fn < 4; ++fn)
          accg[fm][fn] = __builtin_amdgcn_mfma_f32_16x16x32_bf16(af[fm], bf[fn], accg[fm][fn], 0, 0, 0);
      #pragma unroll
      for (int fn = 0; fn < 4; ++fn) {
        const int row = wcol + fn * 16 + (l & 15);
        const int chunk = ((l >> 4) + ks * 4) ^ (row & 7);
        bf[fn] = *(const bf16x8*)&lds[32768 + row * 128 + chunk * 16];
      }
      #pragma unroll
      for (int fm = 0; fm < 4; ++fm)
        #pragma unroll
        for (int fn = 0; fn < 4; ++fn)
          accu[fm][fn] = __builtin_amdgcn_mfma_f32_16x16x32_bf16(af[fm], bf[fn], accu[fm][fn], 0, 0, 0);
    }
  }
  #pragma unroll
  for (int fm = 0; fm < 4; ++fm)
    #pragma unroll
    for (int fn = 0; fn < 4; ++fn)
      #pragma unroll
      for (int r = 0; r < 4; ++r) {
        const int row = m0 + wrow + fm * 16 + (l >> 4) * 4 + r;
        const int col = n0 + wcol + fn * 16 + (l & 15);
        const float g = accg[fm][fn][r];
        const float u = accu[fm][fn][r];
        sg[(size_t)row * 2048 + col] = f2bf(g / (1.0f + __expf(-g)) * u);
      }
}

// ---------------- Flash masked attention, bf16 MFMA, KV-tile = 128 ----------------
// Grid (S/64, H, B), 256 thr = 4 waves; wave w owns q rows w*16..w*16+15.
__global__ __launch_bounds__(256) void flash_mfma_kernel(const ushort* __restrict__ qkv,
                                                         const ushort* __restrict__ vt,
                                                         const ull* __restrict__ pm,
                                                         ushort* __restrict__ att) {
  __shared__ __align__(16) uint8_t Kt[128 * 128];  // [kv][d] 128B rows
  __shared__ __align__(16) uint8_t Vl[64 * 256];   // [d][kv] 256B rows
  __shared__ __align__(16) uint8_t Pl[64 * 256];   // [q][kv] 256B rows
  __shared__ ull Ml[128];                          // [q][2 words]
  const int qt = blockIdx.x, h = blockIdx.y, b = blockIdx.z;
  const int t = threadIdx.x, l = t & 63, wv = t >> 6;

  bf16x8 qf[2];
  {
    const ushort* qrow =
        qkv + (size_t)(b * S_ + qt * 64 + wv * 16 + (l & 15)) * 1024 + h * HD_ + (l >> 4) * 8;
    qf[0] = *(const bf16x8*)qrow;
    qf[1] = *(const bf16x8*)(qrow + 32);
  }
  f32x4 oacc[4] = {};
  float mrow[4] = {-1e30f, -1e30f, -1e30f, -1e30f};
  float lrow[4] = {};

  for (int kt2 = 0; kt2 < S_ / 128; ++kt2) {
    __syncthreads();  // prev tile's reads drained
    // K: 128 rows x 128B; 4 insts/wave (8 rows each)
    #pragma unroll
    for (int i = 0; i < 4; ++i) {
      const int row = wv * 32 + i * 8 + (l >> 3);
      const int g = (l & 7) ^ (row & 7);
      g2lds16(qkv + (size_t)(b * S_ + kt2 * 128 + row) * 1024 + 512 + h * HD_ + g * 8,
              &Kt[(wv * 32 + i * 8) * 128]);
    }
    // V: 64 rows x 256B; 4 insts/wave (4 rows each)
    #pragma unroll
    for (int i = 0; i < 4; ++i) {
      const int d = wv * 16 + i * 4 + (l >> 4);
      const int c = (l & 15) ^ (d & 7);
      g2lds16(vt + ((size_t)(b * 8 + h) * 64 + d) * 1024 + kt2 * 128 + c * 8,
              &Vl[(wv * 16 + i * 4) * 256]);
    }
    if (t < 128) Ml[t] = pm[(size_t)(b * S_ + qt * 64 + (t >> 1)) * 16 + kt2 * 2 + (t & 1)];
    __syncthreads();  // staging complete

    // ---- S = Q K^T (8 col-groups of 16) ----
    f32x4 sacc[8] = {};
    __builtin_amdgcn_s_setprio(1);
    #pragma unroll
    for (int fn = 0; fn < 8; ++fn) {
      const int row = fn * 16 + (l & 15);
      #pragma unroll
      for (int ks = 0; ks < 2; ++ks) {
        const int chunk = ((l >> 4) + ks * 4) ^ (row & 7);
        const bf16x8 kf = *(const bf16x8*)&Kt[row * 128 + chunk * 16];
        sacc[fn] = __builtin_amdgcn_mfma_f32_16x16x32_bf16(qf[ks], kf, sacc[fn], 0, 0, 0);
      }
    }
    __builtin_amdgcn_s_setprio(0);

    // ---- online softmax (rows q=(l>>4)*4+r, cols kv=(l&15)+fn*16) ----
    float p[8][4];
    float corr[4];
    #pragma unroll
    for (int r = 0; r < 4; ++r) {
      const int qloc = wv * 16 + (l >> 4) * 4 + r;
      const ull mw0 = Ml[2 * qloc], mw1 = Ml[2 * qloc + 1];
      float s[8];
      int bit[8];
      float mx = -1e30f;
      #pragma unroll
      for (int fn = 0; fn < 8; ++fn) {
        bit[fn] = (int)(((fn < 4 ? mw0 : mw1) >> ((l & 15) + (fn & 3) * 16)) & 1ull);
        const float sv = bit[fn] ? sacc[fn][r] * 0.125f : -1e30f;
        s[fn] = sv;
        mx = fmaxf(mx, sv);
      }
      mx = fmaxf(mx, __shfl_xor(mx, 1));
      mx = fmaxf(mx, __shfl_xor(mx, 2));
      mx = fmaxf(mx, __shfl_xor(mx, 4));
      mx = fmaxf(mx, __shfl_xor(mx, 8));
      const float mn = fmaxf(mrow[r], mx);
      corr[r] = __expf(mrow[r] - mn);
      mrow[r] = mn;
      float rs = 0.0f;
      #pragma unroll
      for (int fn = 0; fn < 8; ++fn) {
        const float e = bit[fn] ? __expf(s[fn] - mn) : 0.0f;
        p[fn][r] = e;
        rs += e;
      }
      rs += __shfl_xor(rs, 1);
      rs += __shfl_xor(rs, 2);
      rs += __shfl_xor(rs, 4);
      rs += __shfl_xor(rs, 8);
      lrow[r] = lrow[r] * corr[r] + rs;
    }
    #pragma unroll
    for (int fd = 0; fd < 4; ++fd)
      #pragma unroll
      for (int r = 0; r < 4; ++r) oacc[fd][r] *= corr[r];

    // ---- P -> LDS (bf16, swizzled; own wave's 16 rows) ----
    #pragma unroll
    for (int fn = 0; fn < 8; ++fn)
      #pragma unroll
      for (int r = 0; r < 4; ++r) {
        const int ql = (l >> 4) * 4 + r;
        const int kv = (l & 15) + fn * 16;
        *(ushort*)&Pl[(wv * 16 + ql) * 256 + (((kv >> 3) ^ (ql & 7)) * 16) + (kv & 7) * 2] =
            f2bf(p[fn][r]);
      }
    __syncthreads();  // Pl writes visible before PV fragment reads

    // ---- O += P V ----
    bf16x8 pa[4];
    #pragma unroll
    for (int ks = 0; ks < 4; ++ks) {
      const int row = wv * 16 + (l & 15);
      const int chunk = ((l >> 4) + ks * 4) ^ ((l & 15) & 7);
      pa[ks] = *(const bf16x8*)&Pl[row * 256 + chunk * 16];
    }
    __builtin_amdgcn_s_setprio(1);
    #pragma unroll
    for (int fd = 0; fd < 4; ++fd) {
      const int rowd = fd * 16 + (l & 15);
      #pragma unroll
      for (int ks = 0; ks < 4; ++ks) {
        const int chunk = ((l >> 4) + ks * 4) ^ (rowd & 7);
        const bf16x8 vf = *(const bf16x8*)&Vl[rowd * 256 + chunk * 16];
        oacc[fd] = __builtin_amdgcn_mfma_f32_16x16x32_bf16(pa[ks], vf, oacc[fd], 0, 0, 0);
      }
    }
    __builtin_amdgcn_s_setprio(0);
  }

  #pragma unroll
  for (int r = 0; r < 4; ++r) {
    const float inv = 1.0f / fmaxf(lrow[r], 1e-20f);
    #pragma unroll
    for (int fd = 0; fd < 4; ++fd) {
      att[(size_t)(b * S_ + qt * 64 + wv * 16 + (l >> 4) * 4 + r) * D_ + h * HD_ + (l & 15) +
          fd * 16] = f2bf(oacc[fd][r] * inv);
    }
  }
}

extern "C" void kernel_launch(void* const* d_in, const int* in_sizes, int n_in,
                              void* d_out, int out_size, void* d_ws, size_t ws_size,
                              hipStream_t stream) {
  const float* x        = (const float*)d_in[0];
  const float* norm_w   = (const float*)d_in[1];
  const float* attn_w   = (const float*)d_in[2];
  const float* ffn_up   = (const float*)d_in[3];
  const float* ffn_gate = (const float*)d_in[4];
  const float* ffn_down = (const float*)d_in[5];

  float* h = (float*)d_out;
  // ---- workspace layout (≈54.5 MB) ----
  ushort* wt_attn = (ushort*)d_ws;                    // [16][512][512] bf16 (per layer)
  ushort* wt_gu   = wt_attn + (size_t)16 * 512 * 512; // [2][2048][512] bf16 (per layer)
  ushort* wt_down = wt_gu + (size_t)2 * 2048 * 512;   // [512][2048] bf16 (per layer)
  ull*    pmask   = (ull*)(wt_down + (size_t)512 * 2048);  // [4][4096][16]
  ushort* y       = (ushort*)(pmask + 4 * 65536);     // [M][512]
  ushort* qkvbuf  = y + (size_t)M_ * 512;             // [M][1024]  (Q|K)
  ushort* vt      = qkvbuf + (size_t)M_ * 1024;       // [32][64][1024]
  ushort* att     = vt + (size_t)M_ * 512;            // [M][512]
  ushort* sg      = att + (size_t)M_ * 512;           // [M][2048]

  hipMemcpyAsync(h, x, sizeof(float) * (size_t)M_ * D_, hipMemcpyDeviceToDevice, stream);

  const dim3 blk(256);
  maskpack_kernel<<<dim3(256, 4), blk, 0, stream>>>(d_in[6], d_in[7], d_in[8], d_in[9], pmask,
                                                    (const unsigned char*)d_in[9]);

  for (int l = 0; l < L_; ++l) {
    // per-layer weight prep (transpose + bf16 cast)
    wtrans_kernel<<<dim3(16, 16, 16), blk, 0, stream>>>(
        attn_w + (size_t)l * 16 * 512 * 512, wt_attn, 512, 512, 512 * 512, 512 * 512);
    wtrans_kernel<<<dim3(64, 16, 1), blk, 0, stream>>>(
        ffn_gate + (size_t)l * 512 * 2048, wt_gu, 512, 2048, 0, 0);
    wtrans_kernel<<<dim3(64, 16, 1), blk, 0, stream>>>(
        ffn_up + (size_t)l * 512 * 2048, wt_gu + (size_t)2048 * 512, 512, 2048, 0, 0);
    wtrans_kernel<<<dim3(16, 64, 1), blk, 0, stream>>>(
        ffn_down + (size_t)l * 2048 * 512, wt_down, 2048, 512, 0, 0);

    for (int i = 0; i < 4; ++i) {
      rmsnorm_kernel<<<M_ / 4, blk, 0, stream>>>(h, norm_w + (size_t)(l * 5 + i) * D_, y);
      // fused QKV: N=1536; writes Q|K (ldc=1024) + V transposed into vt
      gemm_bf16_kernel<128><<<dim3(12, 32), blk, 0, stream>>>(
          y, 512, wt_attn + (size_t)i * 4 * 512 * 512, 512, qkvbuf, 1024, 2, vt);
      flash_mfma_kernel<<<dim3(16, 8, 4), blk, 0, stream>>>(qkvbuf, vt, pmask + (size_t)i * 65536,
                                                            att);
      // O-proj + residual (BM=64 -> 256 blocks)
      gemm_bf16_kernel<64><<<dim3(4, 64), blk, 0, stream>>>(
          att, 512, wt_attn + (size_t)i * 4 * 512 * 512 + (size_t)1536 * 512, 512, h, 512, 1,
          nullptr);
    }
    rmsnorm_kernel<<<M_ / 4, blk, 0, stream>>>(h, norm_w + (size_t)(l * 5 + 4) * D_, y);
    // fused gate|up + SiLU -> sg [M][2048]
    gemm_gateup_kernel<<<dim3(16, 32), blk, 0, stream>>>(y, wt_gu, wt_gu + (size_t)2048 * 512, sg);
    // down + residual (BM=64 -> 256 blocks)
    gemm_bf16_kernel<64><<<dim3(4, 64), blk, 0, stream>>>(sg, 2048, wt_down, 2048, h, 512, 1,
                                                          nullptr);
  }
}